// Round 3
// baseline (1367.427 us; speedup 1.0000x reference)
//
#include <hip/hip_runtime.h>
#include <hip/hip_bf16.h>

typedef __hip_bfloat16 bf16;

// ---------- dtype-dispatched load/store helpers (bit-level, no bf16 class ops) ----------
__device__ __forceinline__ float ldf(const void* p, size_t i, float isf){
  if (isf > 0.5f) return ((const float*)p)[i];
  unsigned int u = ((unsigned int)((const unsigned short*)p)[i]) << 16;
  return __uint_as_float(u);
}
__device__ __forceinline__ unsigned short f2bf(float v){
  unsigned int u = __float_as_uint(v);
  u = (u + 0x7FFFu + ((u >> 16) & 1u)) >> 16;   // round-to-nearest-even
  return (unsigned short)u;
}

// ---------- diagnostics ----------
__global__ void k_fill(unsigned short* o, unsigned short v, int n){
  int i = blockIdx.x*blockDim.x + threadIdx.x;
  if (i < n) o[i] = v;
}

// ---------- dtype detector: flag[0]=x_is_f32, flag[1]=idx_is_i64 ----------
__global__ void k_detect(const unsigned short* xh, const unsigned int* eu,
                         float* flag, int nelemX, long long E){
  __shared__ int sf32, si64;
  if (threadIdx.x == 0){ sf32 = 0; si64 = 1; }
  __syncthreads();
  int t = threadIdx.x;
  int i = 2*t;                       // even halfword = low half of an f32 (little-endian)
  if (i < nelemX){
    unsigned e8 = (xh[i] >> 7) & 0xFFu;
    if (e8 >= 140u) sf32 = 1;        // bf16 N(0,1) never has exp>=140; f32 mantissa bits do
  }
  if ((long long)(2*t + 1) < 2*E){
    if (eu[2*t + 1] != 0u) si64 = 0; // int64 edge ids < 2^31 -> high words all zero
  }
  __syncthreads();
  if (t == 0){ flag[0] = (float)sf32; flag[1] = (float)si64; }
}

// ---------- degree / dinv ----------
__global__ void k_deg_init(float* d, int n){
  int i = blockIdx.x*blockDim.x + threadIdx.x;
  if (i < n) d[i] = 1.0f;            // self-loop
}
__global__ void k_deg(const int* __restrict__ ei, const float* __restrict__ flag,
                      float* __restrict__ deg, long long E, int n){
  long long i = (long long)blockIdx.x*blockDim.x + threadIdx.x;
  if (i >= E) return;
  int d = (flag[1] > 0.5f) ? ei[2*E + 2*i] : ei[E + i];
  if ((unsigned)d < (unsigned)n) atomicAdd(&deg[d], 1.0f);
}
__global__ void k_rsqrt_(float* d, int n){
  int i = blockIdx.x*blockDim.x + threadIdx.x;
  if (i < n) d[i] = rsqrtf(d[i]);
}

// ---------- layer 1: hs[i,f] = dinv[i]*(x_i . W1[:,f]); acc init = hs ----------
__global__ void k_lin1(const void* __restrict__ x, const void* __restrict__ W,
                       const float* __restrict__ flag, const float* __restrict__ dinv,
                       float* __restrict__ hs, float* __restrict__ acc, int n){
  int t = blockIdx.x*blockDim.x + threadIdx.x;
  int i = t/96, f = t - 96*i;
  if (i >= n) return;
  float isf = flag[0];
  float s = 0.f;
  for (int k = 0; k < 32; ++k)
    s += ldf(x, (size_t)32*i + k, isf) * ldf(W, (size_t)96*k + f, isf);
  s *= dinv[i];
  hs[(size_t)96*i + f] = s;
  acc[(size_t)96*i + f] = s;
}

// ---------- middle layers: y = relu(a[k]*(dinv*in) + c[k]); hs = dinv*(y.W[:,f]) ----------
__global__ void k_lin(const float* __restrict__ in, const void* __restrict__ W,
                      const float* __restrict__ flag, const float* __restrict__ dinv,
                      const float* __restrict__ st,
                      float* __restrict__ hs, float* __restrict__ acc, int n){
  int t = blockIdx.x*blockDim.x + threadIdx.x;
  int i = t/96, f = t - 96*i;
  if (i >= n) return;
  float isf = flag[0];
  float di = dinv[i];
  float s = 0.f;
  for (int k = 0; k < 96; ++k){
    float y = di * in[(size_t)96*i + k] * st[192 + k] + st[288 + k];
    y = fmaxf(y, 0.f);
    s += y * ldf(W, (size_t)96*k + f, isf);
  }
  s *= di;
  hs[(size_t)96*i + f] = s;
  acc[(size_t)96*i + f] = s;
}

__global__ void k_lin4(const float* __restrict__ in, const void* __restrict__ W,
                       const float* __restrict__ flag, const float* __restrict__ dinv,
                       const float* __restrict__ st,
                       float* __restrict__ hs, float* __restrict__ acc, int n){
  int t = blockIdx.x*blockDim.x + threadIdx.x;
  int i = t >> 1, f = t & 1;
  if (i >= n) return;
  float isf = flag[0];
  float di = dinv[i];
  float s = 0.f;
  for (int k = 0; k < 96; ++k){
    float y = di * in[(size_t)96*i + k] * st[192 + k] + st[288 + k];
    y = fmaxf(y, 0.f);
    s += y * ldf(W, (size_t)2*k + f, isf);
  }
  s *= di;
  hs[(size_t)2*i + f] = s;
  acc[(size_t)2*i + f] = s;
}

// ---------- edge scatter: acc[dst,f] += hs[src,f] ----------
__global__ void k_scat96(const int* __restrict__ ei, const float* __restrict__ flag,
                         const float* __restrict__ hs, float* __restrict__ acc,
                         long long E, int n){
  long long t = (long long)blockIdx.x*blockDim.x + threadIdx.x;
  long long ed = t/96; int f = (int)(t - 96*ed);
  if (ed >= E) return;
  int s, d;
  if (flag[1] > 0.5f){ s = ei[2*ed]; d = ei[2*E + 2*ed]; }
  else               { s = ei[ed];   d = ei[E + ed];     }
  if ((unsigned)s < (unsigned)n && (unsigned)d < (unsigned)n)
    atomicAdd(&acc[(size_t)96*d + f], hs[(size_t)96*s + f]);
}
__global__ void k_scat2(const int* __restrict__ ei, const float* __restrict__ flag,
                        const float* __restrict__ hs, float* __restrict__ acc,
                        long long E, int n){
  long long t = (long long)blockIdx.x*blockDim.x + threadIdx.x;
  long long ed = t >> 1; int f = (int)(t & 1);
  if (ed >= E) return;
  int s, d;
  if (flag[1] > 0.5f){ s = ei[2*ed]; d = ei[2*E + 2*ed]; }
  else               { s = ei[ed];   d = ei[E + ed];     }
  if ((unsigned)s < (unsigned)n && (unsigned)d < (unsigned)n)
    atomicAdd(&acc[(size_t)2*d + f], hs[(size_t)2*s + f]);
}

// ---------- batchnorm ----------
__global__ void k_zero(float* p, int n){
  int i = blockIdx.x*blockDim.x + threadIdx.x;
  if (i < n) p[i] = 0.f;
}
// blockDim=(96,4): st[0:96]=sum(y), st[96:192]=sum(y^2), y = dinv*acc
__global__ void k_stats(const float* __restrict__ acc, const float* __restrict__ dinv,
                        float* __restrict__ st, int n){
  int f = threadIdx.x, ty = threadIdx.y;
  float s = 0.f, q = 0.f;
  for (int i = blockIdx.x*4 + ty; i < n; i += gridDim.x*4){
    float y = dinv[i] * acc[(size_t)96*i + f];
    s += y; q += y*y;
  }
  __shared__ float ls[4][96], lq[4][96];
  ls[ty][f] = s; lq[ty][f] = q;
  __syncthreads();
  if (ty == 0){
    s = ls[0][f]+ls[1][f]+ls[2][f]+ls[3][f];
    q = lq[0][f]+lq[1][f]+lq[2][f]+lq[3][f];
    atomicAdd(&st[f], s); atomicAdd(&st[96+f], q);
  }
}
// st[192:288]=a=gamma*istd ; st[288:384]=c=beta-mu*a
__global__ void k_finstats(float* st, const void* __restrict__ g, const void* __restrict__ be,
                           const float* __restrict__ flag, float invN){
  int f = threadIdx.x;
  float isf = flag[0];
  float mu  = st[f]*invN;
  float var = fmaxf(st[96+f]*invN - mu*mu, 0.f);
  float istd = rsqrtf(var + 1e-5f);
  float a = ldf(g, f, isf) * istd;
  st[192+f] = a;
  st[288+f] = ldf(be, f, isf) - mu*a;
}

// ---------- final output (dtype follows input dtype) ----------
__global__ void k_out(const float* __restrict__ dinv, const float* __restrict__ acc4,
                      const void* __restrict__ b4, const float* __restrict__ flag,
                      void* __restrict__ out, int n){
  int i = blockIdx.x*blockDim.x + threadIdx.x;
  if (i >= n) return;
  float isf = flag[0];
  float di = dinv[i];
  float v0 = di*acc4[(size_t)2*i]   + ldf(b4, 0, isf);
  float v1 = di*acc4[(size_t)2*i+1] + ldf(b4, 1, isf);
  if (isf > 0.5f){
    ((float*)out)[(size_t)2*i]   = v0;
    ((float*)out)[(size_t)2*i+1] = v1;
  } else {
    ((unsigned short*)out)[(size_t)2*i]   = f2bf(v0);
    ((unsigned short*)out)[(size_t)2*i+1] = f2bf(v1);
  }
}

extern "C" void kernel_launch(void* const* d_in, const int* in_sizes, int n_in,
                              void* d_out, int out_size, void* d_ws, size_t ws_size,
                              hipStream_t stream)
{
  const int B = 256;
  unsigned short* outh = (unsigned short*)d_out;

  // DIAGNOSTIC 1: pure host-side op, no kernel launch. If only this lands: err ~ 1.02.
  hipMemsetAsync(d_out, 0x3E, (size_t)out_size * 2, stream);

  if (n_in < 16){                                        // err ~ 1.58
    k_fill<<<(out_size+B-1)/B, B, 0, stream>>>(outh, 0x3F40u, out_size); return;
  }
  const int N = in_sizes[0] / 32;
  const long long E = in_sizes[1] / 2;
  if (in_sizes[0] % 32 != 0 || out_size != 2*N){         // err ~ 1.71
    k_fill<<<(out_size+B-1)/B, B, 0, stream>>>(outh, 0x3F60u, out_size); return;
  }
  size_t needF = (size_t)N*(1 + 3*96) + 384 + 2;
  if (ws_size < needF*4){                                // err ~ 1.33
    k_fill<<<(out_size+B-1)/B, B, 0, stream>>>(outh, 0x3F00u, out_size); return;
  }

  const void* x  = d_in[0];
  const int*  ei = (const int*)d_in[1];
  const void* W1 = d_in[2];
  const void* g1 = d_in[4];  const void* be1 = d_in[5];
  const void* W2 = d_in[6];
  const void* g2 = d_in[8];  const void* be2 = d_in[9];
  const void* W3 = d_in[10];
  const void* g3 = d_in[12]; const void* be3 = d_in[13];
  const void* W4 = d_in[14];
  const void* b4 = d_in[15];

  float* ws   = (float*)d_ws;
  float* dinv = ws;                          // N
  float* bufA = dinv + N;                    // 96N
  float* hs   = bufA + (size_t)96*N;         // 96N
  float* bufB = hs   + (size_t)96*N;         // 96N
  float* st   = bufB + (size_t)96*N;         // 384
  float* flag = st + 384;                    // 2

  int gN  = (N + B - 1)/B;
  int gE  = (int)((E + B - 1)/B);
  int gNF = (int)(((size_t)N*96 + B - 1)/B);
  int gEF = (int)((E*96 + B - 1)/B);
  int gN2 = (2*N + B - 1)/B;
  int gE2 = (int)((E*2 + B - 1)/B);
  float invN = 1.0f / (float)N;
  dim3 sblk(96,4);

  // dtype detection
  k_detect<<<1, 256, 0, stream>>>((const unsigned short*)x, (const unsigned int*)ei,
                                  flag, in_sizes[0], E);
  // DIAGNOSTIC 2: kernel canary. If pipeline dies after this: err ~ 0.96.
  k_fill<<<(out_size+B-1)/B, B, 0, stream>>>(outh, 0x3E00u, out_size);

  // degree / dinv
  k_deg_init<<<gN, B, 0, stream>>>(dinv, N);
  k_deg<<<gE, B, 0, stream>>>(ei, flag, dinv, E, N);
  k_rsqrt_<<<gN, B, 0, stream>>>(dinv, N);

  // layer 1: x -> bufA
  k_lin1<<<gNF, B, 0, stream>>>(x, W1, flag, dinv, hs, bufA, N);
  k_scat96<<<gEF, B, 0, stream>>>(ei, flag, hs, bufA, E, N);
  k_zero<<<1, B, 0, stream>>>(st, 192);
  k_stats<<<512, sblk, 0, stream>>>(bufA, dinv, st, N);
  k_finstats<<<1, 96, 0, stream>>>(st, g1, be1, flag, invN);

  // layer 2: bufA -> bufB
  k_lin<<<gNF, B, 0, stream>>>(bufA, W2, flag, dinv, st, hs, bufB, N);
  k_scat96<<<gEF, B, 0, stream>>>(ei, flag, hs, bufB, E, N);
  k_zero<<<1, B, 0, stream>>>(st, 192);
  k_stats<<<512, sblk, 0, stream>>>(bufB, dinv, st, N);
  k_finstats<<<1, 96, 0, stream>>>(st, g2, be2, flag, invN);

  // layer 3: bufB -> bufA
  k_lin<<<gNF, B, 0, stream>>>(bufB, W3, flag, dinv, st, hs, bufA, N);
  k_scat96<<<gEF, B, 0, stream>>>(ei, flag, hs, bufA, E, N);
  k_zero<<<1, B, 0, stream>>>(st, 192);
  k_stats<<<512, sblk, 0, stream>>>(bufA, dinv, st, N);
  k_finstats<<<1, 96, 0, stream>>>(st, g3, be3, flag, invN);

  // layer 4: bufA -> bufB(2N floats); hs reused (2N floats)
  k_lin4<<<gN2, B, 0, stream>>>(bufA, W4, flag, dinv, st, hs, bufB, N);
  k_scat2<<<gE2, B, 0, stream>>>(ei, flag, hs, bufB, E, N);
  k_out<<<gN, B, 0, stream>>>(dinv, bufB, b4, flag, d_out, N);
}

// Round 4
// 607.484 us; speedup vs baseline: 2.2510x; 2.2510x over previous
//
#include <hip/hip_runtime.h>
#include <hip/hip_bf16.h>

// ---------- dtype-dispatched load helpers ----------
__device__ __forceinline__ float ldf(const void* p, size_t i, float isf){
  if (isf > 0.5f) return ((const float*)p)[i];
  unsigned int u = ((unsigned int)((const unsigned short*)p)[i]) << 16;
  return __uint_as_float(u);
}
__device__ __forceinline__ unsigned short f2bf(float v){
  unsigned int u = __float_as_uint(v);
  u = (u + 0x7FFFu + ((u >> 16) & 1u)) >> 16;   // RNE
  return (unsigned short)u;
}

// ---------- diagnostics ----------
__global__ void k_fill(unsigned short* o, unsigned short v, int n){
  int i = blockIdx.x*blockDim.x + threadIdx.x;
  if (i < n) o[i] = v;
}

// ---------- dtype detector: flag[0]=x_is_f32, flag[1]=idx_is_i64 ----------
__global__ void k_detect(const unsigned short* xh, const unsigned int* eu,
                         float* flag, int nelemX, long long E){
  __shared__ int sf32, si64;
  if (threadIdx.x == 0){ sf32 = 0; si64 = 1; }
  __syncthreads();
  int t = threadIdx.x;
  int i = 2*t;
  if (i < nelemX){
    unsigned e8 = (xh[i] >> 7) & 0xFFu;
    if (e8 >= 140u) sf32 = 1;
  }
  if ((long long)(2*t + 1) < 2*E){
    if (eu[2*t + 1] != 0u) si64 = 0;
  }
  __syncthreads();
  if (t == 0){ flag[0] = (float)sf32; flag[1] = (float)si64; }
}

// ---------- weight pre-convert to fp32 workspace ----------
// Wf layout: W1 @0 (3072), W2 @3072 (9216), W3 @12288 (9216), W4 @21504 (192)
__global__ void k_cvtW(const void* W1, const void* W2, const void* W3, const void* W4,
                       const float* __restrict__ flag, float* __restrict__ Wf){
  float isf = flag[0];
  int t = blockIdx.x*blockDim.x + threadIdx.x;
  if (t < 3072)            Wf[t] = ldf(W1, t, isf);
  else if (t < 12288)      Wf[t] = ldf(W2, t - 3072, isf);
  else if (t < 21504)      Wf[t] = ldf(W3, t - 12288, isf);
  else if (t < 21696)      Wf[t] = ldf(W4, t - 21504, isf);
}

// ---------- CSR build ----------
__global__ void k_cnt(const int* __restrict__ ei, const float* __restrict__ flag,
                      int* __restrict__ cnt, long long E, int n){
  long long i = (long long)blockIdx.x*blockDim.x + threadIdx.x;
  if (i >= E) return;
  int d = (flag[1] > 0.5f) ? ei[2*E + 2*i] : ei[E + i];
  if ((unsigned)d < (unsigned)n) atomicAdd(&cnt[d], 1);
}

// single block, 1024 threads: exclusive scan of cnt -> rowst, dinv = rsqrt(1+cnt)
__global__ void k_scan(const int* __restrict__ cnt, int* __restrict__ rowst,
                       float* __restrict__ dinv, int n){
  __shared__ int woff[16];
  __shared__ int chtot;
  __shared__ int carry_s;
  int tid = threadIdx.x;
  int lane = tid & 63, wid = tid >> 6;
  if (tid == 0) carry_s = 0;
  __syncthreads();
  for (int base = 0; base < n; base += 1024){
    int i = base + tid;
    int v = (i < n) ? cnt[i] : 0;
    int s = v;
    #pragma unroll
    for (int off = 1; off < 64; off <<= 1){
      int t = __shfl_up(s, off, 64);
      if (lane >= off) s += t;
    }
    if (lane == 63) woff[wid] = s;
    __syncthreads();
    if (tid < 16){
      int w = woff[tid];
      int ws_ = w;
      #pragma unroll
      for (int off = 1; off < 16; off <<= 1){
        int t = __shfl_up(ws_, off, 64);
        if (tid >= off) ws_ += t;
      }
      woff[tid] = ws_ - w;            // exclusive wave offset
      if (tid == 15) chtot = ws_;     // chunk total
    }
    __syncthreads();
    int carry = carry_s;
    if (i < n){
      rowst[i] = carry + woff[wid] + s - v;
      dinv[i]  = rsqrtf((float)(1 + v));   // +1 self-loop
    }
    __syncthreads();
    if (tid == 0) carry_s = carry + chtot;
  }
  __syncthreads();
  if (tid == 0) rowst[n] = carry_s;
}

__global__ void k_fill_slots(const int* __restrict__ ei, const float* __restrict__ flag,
                             const int* __restrict__ rowst, int* __restrict__ cursor,
                             int* __restrict__ csr, long long E, int n){
  long long i = (long long)blockIdx.x*blockDim.x + threadIdx.x;
  if (i >= E) return;
  int s, d;
  if (flag[1] > 0.5f){ s = ei[2*i]; d = ei[2*E + 2*i]; }
  else               { s = ei[i];   d = ei[E + i];     }
  if ((unsigned)s < (unsigned)n && (unsigned)d < (unsigned)n){
    int p = atomicAdd(&cursor[d], 1);
    csr[rowst[d] + p] = s;
  }
}

// ---------- layer GEMMs (fp32 weights via wave-uniform s_loads, thread = node) ----------
__global__ __launch_bounds__(256) void k_lin1(const void* __restrict__ x,
      const float* __restrict__ Wf, const float* __restrict__ flag,
      const float* __restrict__ dinv, float* __restrict__ hs, int n){
  int i = blockIdx.x*blockDim.x + threadIdx.x;
  if (i >= n) return;
  float isf = flag[0];
  float acc[96];
  #pragma unroll
  for (int f = 0; f < 96; ++f) acc[f] = 0.f;
  for (int k = 0; k < 32; ++k){
    float xk = ldf(x, (size_t)32*i + k, isf);
    const float4* wr = (const float4*)(Wf + 96*k);
    #pragma unroll
    for (int f4 = 0; f4 < 24; ++f4){
      float4 w = wr[f4];
      acc[4*f4]   += xk*w.x; acc[4*f4+1] += xk*w.y;
      acc[4*f4+2] += xk*w.z; acc[4*f4+3] += xk*w.w;
    }
  }
  float di = dinv[i];
  float4* hp = (float4*)(hs + (size_t)96*i);
  #pragma unroll
  for (int f4 = 0; f4 < 24; ++f4)
    hp[f4] = make_float4(di*acc[4*f4], di*acc[4*f4+1], di*acc[4*f4+2], di*acc[4*f4+3]);
}

// mid layers: y = relu(a[k]*z + c[k]); hs = dinv*(y.W)
__global__ __launch_bounds__(256) void k_lin(const float* __restrict__ z,
      const float* __restrict__ Wf, const float* __restrict__ st,
      const float* __restrict__ dinv, float* __restrict__ hs, int n){
  int i = blockIdx.x*blockDim.x + threadIdx.x;
  if (i >= n) return;
  float acc[96];
  #pragma unroll
  for (int f = 0; f < 96; ++f) acc[f] = 0.f;
  const float* zr = z + (size_t)96*i;
  #pragma unroll 4
  for (int k = 0; k < 96; ++k){
    float y = fmaxf(zr[k]*st[192+k] + st[288+k], 0.f);
    const float4* wr = (const float4*)(Wf + 96*k);
    #pragma unroll
    for (int f4 = 0; f4 < 24; ++f4){
      float4 w = wr[f4];
      acc[4*f4]   += y*w.x; acc[4*f4+1] += y*w.y;
      acc[4*f4+2] += y*w.z; acc[4*f4+3] += y*w.w;
    }
  }
  float di = dinv[i];
  float4* hp = (float4*)(hs + (size_t)96*i);
  #pragma unroll
  for (int f4 = 0; f4 < 24; ++f4)
    hp[f4] = make_float4(di*acc[4*f4], di*acc[4*f4+1], di*acc[4*f4+2], di*acc[4*f4+3]);
}

__global__ __launch_bounds__(256) void k_lin4(const float* __restrict__ z,
      const float* __restrict__ Wf, const float* __restrict__ st,
      const float* __restrict__ dinv, float* __restrict__ hs2, int n){
  int i = blockIdx.x*blockDim.x + threadIdx.x;
  if (i >= n) return;
  const float* zr = z + (size_t)96*i;
  float a0 = 0.f, a1 = 0.f;
  #pragma unroll 8
  for (int k = 0; k < 96; ++k){
    float y = fmaxf(zr[k]*st[192+k] + st[288+k], 0.f);
    a0 += y*Wf[2*k]; a1 += y*Wf[2*k+1];
  }
  float di = dinv[i];
  hs2[(size_t)2*i]   = di*a0;
  hs2[(size_t)2*i+1] = di*a1;
}

// ---------- CSR gather aggregation: z[d] = dinv[d]*(hs[d] + sum_e hs[src]) ----------
// blockDim (24,8): 24 float4-lanes per node, 8 nodes/block. block 0 also zeros st[0:192].
__global__ void k_agg(const float4* __restrict__ hs4, const int* __restrict__ rowst,
                      const int* __restrict__ csr, const float* __restrict__ dinv,
                      float4* __restrict__ z4, float* __restrict__ st, int n){
  int t = threadIdx.y*24 + threadIdx.x;
  if (blockIdx.x == 0 && t < 192) st[t] = 0.f;
  int node = blockIdx.x*8 + threadIdx.y;
  if (node >= n) return;
  int g = threadIdx.x;
  float4 a = hs4[(size_t)node*24 + g];          // self-loop
  int b = rowst[node], e = rowst[node+1];
  for (int j = b; j < e; ++j){
    int s = csr[j];
    float4 v = hs4[(size_t)s*24 + g];
    a.x += v.x; a.y += v.y; a.z += v.z; a.w += v.w;
  }
  float di = dinv[node];
  a.x *= di; a.y *= di; a.z *= di; a.w *= di;
  z4[(size_t)node*24 + g] = a;
}

// final layer aggregation + bias + output convert
__global__ void k_agg2(const float2* __restrict__ hs2, const int* __restrict__ rowst,
                       const int* __restrict__ csr, const float* __restrict__ dinv,
                       const void* __restrict__ b4, const float* __restrict__ flag,
                       void* __restrict__ out, int n){
  int node = blockIdx.x*blockDim.x + threadIdx.x;
  if (node >= n) return;
  float2 a = hs2[node];
  int b = rowst[node], e = rowst[node+1];
  for (int j = b; j < e; ++j){
    float2 v = hs2[csr[j]];
    a.x += v.x; a.y += v.y;
  }
  float isf = flag[0];
  float di = dinv[node];
  float v0 = a.x*di + ldf(b4, 0, isf);
  float v1 = a.y*di + ldf(b4, 1, isf);
  if (isf > 0.5f){
    ((float*)out)[(size_t)2*node]   = v0;
    ((float*)out)[(size_t)2*node+1] = v1;
  } else {
    ((unsigned short*)out)[(size_t)2*node]   = f2bf(v0);
    ((unsigned short*)out)[(size_t)2*node+1] = f2bf(v1);
  }
}

// ---------- batchnorm ----------
__global__ void k_stats(const float* __restrict__ z, float* __restrict__ st, int n){
  int f = threadIdx.x, ty = threadIdx.y;
  float s = 0.f, q = 0.f;
  for (int i = blockIdx.x*4 + ty; i < n; i += gridDim.x*4){
    float y = z[(size_t)96*i + f];
    s += y; q += y*y;
  }
  __shared__ float ls[4][96], lq[4][96];
  ls[ty][f] = s; lq[ty][f] = q;
  __syncthreads();
  if (ty == 0){
    s = ls[0][f]+ls[1][f]+ls[2][f]+ls[3][f];
    q = lq[0][f]+lq[1][f]+lq[2][f]+lq[3][f];
    atomicAdd(&st[f], s); atomicAdd(&st[96+f], q);
  }
}
__global__ void k_finstats(float* st, const void* __restrict__ g, const void* __restrict__ be,
                           const float* __restrict__ flag, float invN){
  int f = threadIdx.x;
  float isf = flag[0];
  float mu  = st[f]*invN;
  float var = fmaxf(st[96+f]*invN - mu*mu, 0.f);
  float istd = rsqrtf(var + 1e-5f);
  float a = ldf(g, f, isf) * istd;
  st[192+f] = a;
  st[288+f] = ldf(be, f, isf) - mu*a;
}

extern "C" void kernel_launch(void* const* d_in, const int* in_sizes, int n_in,
                              void* d_out, int out_size, void* d_ws, size_t ws_size,
                              hipStream_t stream)
{
  const int B = 256;
  unsigned short* outh = (unsigned short*)d_out;

  if (n_in < 16){
    k_fill<<<(out_size+B-1)/B, B, 0, stream>>>(outh, 0x3F40u, out_size); return;
  }
  const int N = in_sizes[0] / 32;
  const long long E = in_sizes[1] / 2;
  if (in_sizes[0] % 32 != 0 || out_size != 2*N){
    k_fill<<<(out_size+B-1)/B, B, 0, stream>>>(outh, 0x3F60u, out_size); return;
  }

  // workspace layout (floats)
  size_t Npad = ((size_t)N + 3) & ~(size_t)3;
  float* ws   = (float*)d_ws;
  float* dinv = ws;                              // Npad
  float* Z    = dinv + Npad;                     // 96N
  float* HS   = Z + (size_t)96*N;                // 96N
  float* hs2  = HS + (size_t)96*N;               // 2N
  float* st   = hs2 + (size_t)2*N;               // 384
  float* flag = st + 384;                        // 4
  int*   cnt    = (int*)(flag + 4);              // N
  int*   cursor = cnt + N;                       // N   (adjacent to cnt: one memset)
  int*   rowst  = cursor + N;                    // N+1
  int*   csr    = rowst + N + 1;                 // E
  float* Wf     = (float*)(csr + E);             // 21696
  size_t needF = Npad + (size_t)96*N*2 + (size_t)2*N + 388 + (size_t)(3*N+1) + (size_t)E + 21696;
  if (ws_size < needF*4){
    k_fill<<<(out_size+B-1)/B, B, 0, stream>>>(outh, 0x3F00u, out_size); return;
  }

  const void* x  = d_in[0];
  const int*  ei = (const int*)d_in[1];
  const void* W1 = d_in[2];
  const void* g1 = d_in[4];  const void* be1 = d_in[5];
  const void* W2 = d_in[6];
  const void* g2 = d_in[8];  const void* be2 = d_in[9];
  const void* W3 = d_in[10];
  const void* g3 = d_in[12]; const void* be3 = d_in[13];
  const void* W4 = d_in[14];
  const void* b4 = d_in[15];

  int gN  = (N + B - 1)/B;
  int gE  = (int)((E + B - 1)/B);
  int gA  = (N + 7)/8;
  float invN = 1.0f / (float)N;
  dim3 ablk(24,8);
  dim3 sblk(96,4);

  // dtype detection + weight convert + CSR build
  k_detect<<<1, 256, 0, stream>>>((const unsigned short*)x, (const unsigned int*)ei,
                                  flag, in_sizes[0], E);
  hipMemsetAsync(cnt, 0, (size_t)2*N*sizeof(int), stream);   // cnt + cursor
  k_cvtW<<<(21696+B-1)/B, B, 0, stream>>>(W1, W2, W3, W4, flag, Wf);
  k_cnt<<<gE, B, 0, stream>>>(ei, flag, cnt, E, N);
  k_scan<<<1, 1024, 0, stream>>>(cnt, rowst, dinv, N);
  k_fill_slots<<<gE, B, 0, stream>>>(ei, flag, rowst, cursor, csr, E, N);

  // layer 1: x -> HS -> Z
  k_lin1<<<gN, B, 0, stream>>>(x, Wf, flag, dinv, HS, N);
  k_agg<<<gA, ablk, 0, stream>>>((const float4*)HS, rowst, csr, dinv, (float4*)Z, st, N);
  k_stats<<<512, sblk, 0, stream>>>(Z, st, N);
  k_finstats<<<1, 96, 0, stream>>>(st, g1, be1, flag, invN);

  // layer 2: Z -> HS -> Z
  k_lin<<<gN, B, 0, stream>>>(Z, Wf + 3072, st, dinv, HS, N);
  k_agg<<<gA, ablk, 0, stream>>>((const float4*)HS, rowst, csr, dinv, (float4*)Z, st, N);
  k_stats<<<512, sblk, 0, stream>>>(Z, st, N);
  k_finstats<<<1, 96, 0, stream>>>(st, g2, be2, flag, invN);

  // layer 3: Z -> HS -> Z
  k_lin<<<gN, B, 0, stream>>>(Z, Wf + 12288, st, dinv, HS, N);
  k_agg<<<gA, ablk, 0, stream>>>((const float4*)HS, rowst, csr, dinv, (float4*)Z, st, N);
  k_stats<<<512, sblk, 0, stream>>>(Z, st, N);
  k_finstats<<<1, 96, 0, stream>>>(st, g3, be3, flag, invN);

  // layer 4: Z -> hs2 -> out
  k_lin4<<<gN, B, 0, stream>>>(Z, Wf + 21504, st, dinv, hs2, N);
  k_agg2<<<gN, B, 0, stream>>>((const float2*)hs2, rowst, csr, dinv, b4, flag, d_out, N);
}

// Round 5
// 602.079 us; speedup vs baseline: 2.2712x; 1.0090x over previous
//
#include <hip/hip_runtime.h>
#include <hip/hip_bf16.h>

// ---------- dtype-dispatched load helpers ----------
__device__ __forceinline__ float ldf(const void* p, size_t i, float isf){
  if (isf > 0.5f) return ((const float*)p)[i];
  unsigned int u = ((unsigned int)((const unsigned short*)p)[i]) << 16;
  return __uint_as_float(u);
}
__device__ __forceinline__ unsigned short f2bf(float v){
  unsigned int u = __float_as_uint(v);
  u = (u + 0x7FFFu + ((u >> 16) & 1u)) >> 16;   // RNE
  return (unsigned short)u;
}
__device__ __forceinline__ unsigned int pk2(float a, float b){
  return (unsigned int)f2bf(a) | ((unsigned int)f2bf(b) << 16);
}
__device__ __forceinline__ float lo16(unsigned int u){ return __uint_as_float(u << 16); }
__device__ __forceinline__ float hi16(unsigned int u){ return __uint_as_float(u & 0xFFFF0000u); }

// ---------- diagnostics ----------
__global__ void k_fill(unsigned short* o, unsigned short v, int n){
  int i = blockIdx.x*blockDim.x + threadIdx.x;
  if (i < n) o[i] = v;
}

// ---------- dtype detector: flag[0]=x_is_f32, flag[1]=idx_is_i64 ----------
__global__ void k_detect(const unsigned short* xh, const unsigned int* eu,
                         float* flag, int nelemX, long long E){
  __shared__ int sf32, si64;
  if (threadIdx.x == 0){ sf32 = 0; si64 = 1; }
  __syncthreads();
  int t = threadIdx.x;
  int i = 2*t;
  if (i < nelemX){
    unsigned e8 = (xh[i] >> 7) & 0xFFu;
    if (e8 >= 140u) sf32 = 1;
  }
  if ((long long)(2*t + 1) < 2*E){
    if (eu[2*t + 1] != 0u) si64 = 0;
  }
  __syncthreads();
  if (t == 0){ flag[0] = (float)sf32; flag[1] = (float)si64; }
}

// ---------- weight pre-convert ----------
__global__ void k_cvtW(const void* W1, const void* W2, const void* W3, const void* W4,
                       const float* __restrict__ flag, float* __restrict__ Wf){
  float isf = flag[0];
  int t = blockIdx.x*blockDim.x + threadIdx.x;
  if (t < 3072)            Wf[t] = ldf(W1, t, isf);
  else if (t < 12288)      Wf[t] = ldf(W2, t - 3072, isf);
  else if (t < 21504)      Wf[t] = ldf(W3, t - 12288, isf);
  else if (t < 21696)      Wf[t] = ldf(W4, t - 21504, isf);
}

// ---------- CSR build ----------
__global__ void k_cnt(const int* __restrict__ ei, const float* __restrict__ flag,
                      int* __restrict__ cnt, long long E, int n){
  long long i = (long long)blockIdx.x*blockDim.x + threadIdx.x;
  if (i >= E) return;
  int d = (flag[1] > 0.5f) ? ei[2*E + 2*i] : ei[E + i];
  if ((unsigned)d < (unsigned)n) atomicAdd(&cnt[d], 1);
}

__global__ void k_bsum(const int* __restrict__ cnt, int* __restrict__ bsum, int n){
  int i = blockIdx.x*256 + threadIdx.x;
  int v = (i < n) ? cnt[i] : 0;
  #pragma unroll
  for (int off = 32; off; off >>= 1) v += __shfl_down(v, off, 64);
  __shared__ int w[4];
  if ((threadIdx.x & 63) == 0) w[threadIdx.x >> 6] = v;
  __syncthreads();
  if (threadIdx.x == 0) bsum[blockIdx.x] = w[0]+w[1]+w[2]+w[3];
}

// 1 block, 256 threads: exclusive scan of bsum[nb] -> boff; rowstN = total
__global__ void k_sscan(const int* __restrict__ bsum, int* __restrict__ boff,
                        int* __restrict__ rowstN, int nb){
  int t = threadIdx.x;
  int v = (t < nb) ? bsum[t] : 0;
  int lane = t & 63, wid = t >> 6;
  int s = v;
  #pragma unroll
  for (int off = 1; off < 64; off <<= 1){
    int u = __shfl_up(s, off, 64);
    if (lane >= off) s += u;
  }
  __shared__ int wt[4];
  if (lane == 63) wt[wid] = s;
  __syncthreads();
  int add = 0;
  for (int w = 0; w < wid; ++w) add += wt[w];
  int incl = s + add;
  if (t < nb) boff[t] = incl - v;
  if (t == nb - 1) *rowstN = incl;
}

__global__ void k_emit(const int* __restrict__ cnt, const int* __restrict__ boff,
                       int* __restrict__ rowst, float* __restrict__ dinv, int n){
  int i = blockIdx.x*256 + threadIdx.x;
  int v = (i < n) ? cnt[i] : 0;
  int lane = threadIdx.x & 63, wid = threadIdx.x >> 6;
  int s = v;
  #pragma unroll
  for (int off = 1; off < 64; off <<= 1){
    int u = __shfl_up(s, off, 64);
    if (lane >= off) s += u;
  }
  __shared__ int wt[4];
  if (lane == 63) wt[wid] = s;
  __syncthreads();
  int add = 0;
  for (int w = 0; w < wid; ++w) add += wt[w];
  if (i < n){
    rowst[i] = boff[blockIdx.x] + add + s - v;
    dinv[i]  = rsqrtf((float)(1 + v));
  }
}

__global__ void k_fill_slots(const int* __restrict__ ei, const float* __restrict__ flag,
                             const int* __restrict__ rowst, int* __restrict__ cursor,
                             int* __restrict__ csr, long long E, int n){
  long long i = (long long)blockIdx.x*blockDim.x + threadIdx.x;
  if (i >= E) return;
  int s, d;
  if (flag[1] > 0.5f){ s = ei[2*i]; d = ei[2*E + 2*i]; }
  else               { s = ei[i];   d = ei[E + i];     }
  if ((unsigned)s < (unsigned)n && (unsigned)d < (unsigned)n){
    int p = atomicAdd(&cursor[d], 1);
    csr[rowst[d] + p] = s;
  }
}

// ---------- layer 1: x -> HS (bf16) ----------
__global__ __launch_bounds__(256) void k_lin1(const void* __restrict__ x,
      const float* __restrict__ Wf, const float* __restrict__ flag,
      const float* __restrict__ dinv, unsigned short* __restrict__ HS, int n){
  int i = blockIdx.x*blockDim.x + threadIdx.x;
  if (i >= n) return;
  float isf = flag[0];
  float acc[96];
  #pragma unroll
  for (int f = 0; f < 96; ++f) acc[f] = 0.f;
  for (int k = 0; k < 32; ++k){
    float xk = ldf(x, (size_t)32*i + k, isf);
    const float4* wr = (const float4*)(Wf + 96*k);
    #pragma unroll
    for (int f4 = 0; f4 < 24; ++f4){
      float4 w = wr[f4];
      acc[4*f4]   += xk*w.x; acc[4*f4+1] += xk*w.y;
      acc[4*f4+2] += xk*w.z; acc[4*f4+3] += xk*w.w;
    }
  }
  float di = dinv[i];
  uint4* hp = (uint4*)(HS + (size_t)96*i);
  #pragma unroll
  for (int q = 0; q < 12; ++q){
    uint4 o;
    o.x = pk2(di*acc[8*q],   di*acc[8*q+1]);
    o.y = pk2(di*acc[8*q+2], di*acc[8*q+3]);
    o.z = pk2(di*acc[8*q+4], di*acc[8*q+5]);
    o.w = pk2(di*acc[8*q+6], di*acc[8*q+7]);
    hp[q] = o;
  }
}

// ---------- mid layers: BN(st)+ReLU+GEMM -> HS (bf16); a,c computed in-block ----------
__global__ __launch_bounds__(256) void k_lin(const float* __restrict__ z,
      const float* __restrict__ Wf, const float* __restrict__ st,
      const void* __restrict__ gam, const void* __restrict__ bet,
      const float* __restrict__ flag, const float* __restrict__ dinv,
      unsigned short* __restrict__ HS, int n, float invN){
  __shared__ float sa[96], sc[96];
  int t = threadIdx.x;
  if (t < 96){
    float isf = flag[0];
    float mu  = st[t]*invN;
    float var = fmaxf(st[96+t]*invN - mu*mu, 0.f);
    float istd = rsqrtf(var + 1e-5f);
    float a = ldf(gam, t, isf)*istd;
    sa[t] = a; sc[t] = ldf(bet, t, isf) - mu*a;
  }
  __syncthreads();
  int i = blockIdx.x*blockDim.x + t;
  if (i >= n) return;
  float acc[96];
  #pragma unroll
  for (int f = 0; f < 96; ++f) acc[f] = 0.f;
  const float* zr = z + (size_t)96*i;
  #pragma unroll 4
  for (int k = 0; k < 96; ++k){
    float y = fmaxf(zr[k]*sa[k] + sc[k], 0.f);
    const float4* wr = (const float4*)(Wf + 96*k);
    #pragma unroll
    for (int f4 = 0; f4 < 24; ++f4){
      float4 w = wr[f4];
      acc[4*f4]   += y*w.x; acc[4*f4+1] += y*w.y;
      acc[4*f4+2] += y*w.z; acc[4*f4+3] += y*w.w;
    }
  }
  float di = dinv[i];
  uint4* hp = (uint4*)(HS + (size_t)96*i);
  #pragma unroll
  for (int q = 0; q < 12; ++q){
    uint4 o;
    o.x = pk2(di*acc[8*q],   di*acc[8*q+1]);
    o.y = pk2(di*acc[8*q+2], di*acc[8*q+3]);
    o.z = pk2(di*acc[8*q+4], di*acc[8*q+5]);
    o.w = pk2(di*acc[8*q+6], di*acc[8*q+7]);
    hp[q] = o;
  }
}

__global__ __launch_bounds__(256) void k_lin4(const float* __restrict__ z,
      const float* __restrict__ Wf, const float* __restrict__ st,
      const void* __restrict__ gam, const void* __restrict__ bet,
      const float* __restrict__ flag, const float* __restrict__ dinv,
      float* __restrict__ hs2, int n, float invN){
  __shared__ float sa[96], sc[96];
  int t = threadIdx.x;
  if (t < 96){
    float isf = flag[0];
    float mu  = st[t]*invN;
    float var = fmaxf(st[96+t]*invN - mu*mu, 0.f);
    float istd = rsqrtf(var + 1e-5f);
    float a = ldf(gam, t, isf)*istd;
    sa[t] = a; sc[t] = ldf(bet, t, isf) - mu*a;
  }
  __syncthreads();
  int i = blockIdx.x*blockDim.x + t;
  if (i >= n) return;
  const float* zr = z + (size_t)96*i;
  float a0 = 0.f, a1 = 0.f;
  #pragma unroll 8
  for (int k = 0; k < 96; ++k){
    float y = fmaxf(zr[k]*sa[k] + sc[k], 0.f);
    a0 += y*Wf[2*k]; a1 += y*Wf[2*k+1];
  }
  float di = dinv[i];
  hs2[(size_t)2*i]   = di*a0;
  hs2[(size_t)2*i+1] = di*a1;
}

// ---------- CSR gather aggregation (bf16 HS): z[d] = dinv[d]*(hs[d] + sum hs[src]) ----------
// blockDim (12,16): 12 uint4-lanes (8 bf16 each) per node, 16 nodes/block.
#define ACC8(v) { a0+=lo16((v).x); a1+=hi16((v).x); a2+=lo16((v).y); a3+=hi16((v).y); \
                  a4+=lo16((v).z); a5+=hi16((v).z); a6+=lo16((v).w); a7+=hi16((v).w); }
__global__ __launch_bounds__(192) void k_agg(const uint4* __restrict__ hsr,
      const int* __restrict__ rowst, const int* __restrict__ csr,
      const float* __restrict__ dinv, float4* __restrict__ z4,
      float* __restrict__ st, int n){
  int t = threadIdx.y*12 + threadIdx.x;
  if (blockIdx.x == 0 && t < 192) st[t] = 0.f;   // zero stats for the following k_stats
  int node = blockIdx.x*16 + threadIdx.y;
  if (node >= n) return;
  int g = threadIdx.x;
  uint4 v = hsr[(size_t)node*12 + g];            // self-loop term
  float a0 = lo16(v.x), a1 = hi16(v.x), a2 = lo16(v.y), a3 = hi16(v.y);
  float a4 = lo16(v.z), a5 = hi16(v.z), a6 = lo16(v.w), a7 = hi16(v.w);
  int b = rowst[node], e = rowst[node+1];
  int j = b;
  for (; j + 3 < e; j += 4){
    int s0 = csr[j], s1 = csr[j+1], s2 = csr[j+2], s3 = csr[j+3];
    uint4 v0 = hsr[(size_t)s0*12 + g];
    uint4 v1 = hsr[(size_t)s1*12 + g];
    uint4 v2 = hsr[(size_t)s2*12 + g];
    uint4 v3 = hsr[(size_t)s3*12 + g];
    ACC8(v0); ACC8(v1); ACC8(v2); ACC8(v3);
  }
  for (; j < e; ++j){
    uint4 vv = hsr[(size_t)csr[j]*12 + g];
    ACC8(vv);
  }
  float di = dinv[node];
  z4[(size_t)node*24 + 2*g]     = make_float4(a0*di, a1*di, a2*di, a3*di);
  z4[(size_t)node*24 + 2*g + 1] = make_float4(a4*di, a5*di, a6*di, a7*di);
}

// final layer aggregation + bias + output convert (hs2 fp32)
__global__ void k_agg2(const float2* __restrict__ hs2, const int* __restrict__ rowst,
                       const int* __restrict__ csr, const float* __restrict__ dinv,
                       const void* __restrict__ b4, const float* __restrict__ flag,
                       void* __restrict__ out, int n){
  int node = blockIdx.x*blockDim.x + threadIdx.x;
  if (node >= n) return;
  float2 a = hs2[node];
  int b = rowst[node], e = rowst[node+1];
  for (int j = b; j < e; ++j){
    float2 v = hs2[csr[j]];
    a.x += v.x; a.y += v.y;
  }
  float isf = flag[0];
  float di = dinv[node];
  float v0 = a.x*di + ldf(b4, 0, isf);
  float v1 = a.y*di + ldf(b4, 1, isf);
  if (isf > 0.5f){
    ((float*)out)[(size_t)2*node]   = v0;
    ((float*)out)[(size_t)2*node+1] = v1;
  } else {
    ((unsigned short*)out)[(size_t)2*node]   = f2bf(v0);
    ((unsigned short*)out)[(size_t)2*node+1] = f2bf(v1);
  }
}

// ---------- batchnorm stats (sums into st[0:192], zeroed by preceding k_agg) ----------
__global__ void k_stats(const float* __restrict__ z, float* __restrict__ st, int n){
  int f = threadIdx.x, ty = threadIdx.y;
  float s = 0.f, q = 0.f;
  for (int i = blockIdx.x*4 + ty; i < n; i += gridDim.x*4){
    float y = z[(size_t)96*i + f];
    s += y; q += y*y;
  }
  __shared__ float ls[4][96], lq[4][96];
  ls[ty][f] = s; lq[ty][f] = q;
  __syncthreads();
  if (ty == 0){
    s = ls[0][f]+ls[1][f]+ls[2][f]+ls[3][f];
    q = lq[0][f]+lq[1][f]+lq[2][f]+lq[3][f];
    atomicAdd(&st[f], s); atomicAdd(&st[96+f], q);
  }
}

extern "C" void kernel_launch(void* const* d_in, const int* in_sizes, int n_in,
                              void* d_out, int out_size, void* d_ws, size_t ws_size,
                              hipStream_t stream)
{
  const int B = 256;
  unsigned short* outh = (unsigned short*)d_out;

  if (n_in < 16){
    k_fill<<<(out_size+B-1)/B, B, 0, stream>>>(outh, 0x3F40u, out_size); return;
  }
  const int N = in_sizes[0] / 32;
  const long long E = in_sizes[1] / 2;
  if (in_sizes[0] % 32 != 0 || out_size != 2*N){
    k_fill<<<(out_size+B-1)/B, B, 0, stream>>>(outh, 0x3F60u, out_size); return;
  }

  // ---- workspace layout ----
  size_t Npad = ((size_t)N + 3) & ~(size_t)3;
  float* ws   = (float*)d_ws;
  float* dinv = ws;                               // Npad
  float* Z    = dinv + Npad;                      // 96N (fp32)
  float* hs2  = Z + (size_t)96*N;                 // 2N
  float* st   = hs2 + (size_t)2*N;                // 384 (sums only; padded)
  float* flag = st + 384;                         // 4
  float* Wf   = flag + 4;                         // 21696
  int* cnt    = (int*)(Wf + 21696);               // N
  int* cursor = cnt + N;                          // N (adjacent: one memset)
  int* rowst  = cursor + N;                       // N+1
  int* bsum   = rowst + N + 1;                    // 256
  int* boff   = bsum + 256;                       // 256
  int* csr    = boff + 256;                       // E
  uintptr_t hp_ = (uintptr_t)(csr + E);
  hp_ = (hp_ + 15) & ~(uintptr_t)15;
  unsigned short* HS = (unsigned short*)hp_;      // 96N bf16, 16B-aligned

  size_t needB = (hp_ - (uintptr_t)d_ws) + (size_t)96*N*2 + 64;
  if (ws_size < needB){
    k_fill<<<(out_size+B-1)/B, B, 0, stream>>>(outh, 0x3F00u, out_size); return;
  }

  const void* x  = d_in[0];
  const int*  ei = (const int*)d_in[1];
  const void* W1 = d_in[2];
  const void* g1 = d_in[4];  const void* be1 = d_in[5];
  const void* W2 = d_in[6];
  const void* g2 = d_in[8];  const void* be2 = d_in[9];
  const void* W3 = d_in[10];
  const void* g3 = d_in[12]; const void* be3 = d_in[13];
  const void* W4 = d_in[14];
  const void* b4 = d_in[15];

  int gN  = (N + B - 1)/B;
  int gE  = (int)((E + B - 1)/B);
  int nb  = (N + 255)/256;            // <= 256 assumed (N <= 65536)
  int gA  = (N + 15)/16;
  float invN = 1.0f / (float)N;
  dim3 ablk(12,16);
  dim3 sblk(96,4);

  // dtype detection + weight convert + CSR build
  k_detect<<<1, 256, 0, stream>>>((const unsigned short*)x, (const unsigned int*)ei,
                                  flag, in_sizes[0], E);
  hipMemsetAsync(cnt, 0, (size_t)2*N*sizeof(int), stream);   // cnt + cursor
  k_cvtW<<<(21696+B-1)/B, B, 0, stream>>>(W1, W2, W3, W4, flag, Wf);
  k_cnt<<<gE, B, 0, stream>>>(ei, flag, cnt, E, N);
  k_bsum<<<nb, 256, 0, stream>>>(cnt, bsum, N);
  k_sscan<<<1, 256, 0, stream>>>(bsum, boff, rowst + N, nb);
  k_emit<<<nb, 256, 0, stream>>>(cnt, boff, rowst, dinv, N);
  k_fill_slots<<<gE, B, 0, stream>>>(ei, flag, rowst, cursor, csr, E, N);

  // layer 1
  k_lin1<<<gN, B, 0, stream>>>(x, Wf, flag, dinv, HS, N);
  k_agg<<<gA, ablk, 0, stream>>>((const uint4*)HS, rowst, csr, dinv, (float4*)Z, st, N);
  k_stats<<<512, sblk, 0, stream>>>(Z, st, N);

  // layer 2
  k_lin<<<gN, B, 0, stream>>>(Z, Wf + 3072, st, g1, be1, flag, dinv, HS, N, invN);
  k_agg<<<gA, ablk, 0, stream>>>((const uint4*)HS, rowst, csr, dinv, (float4*)Z, st, N);
  k_stats<<<512, sblk, 0, stream>>>(Z, st, N);

  // layer 3
  k_lin<<<gN, B, 0, stream>>>(Z, Wf + 12288, st, g2, be2, flag, dinv, HS, N, invN);
  k_agg<<<gA, ablk, 0, stream>>>((const uint4*)HS, rowst, csr, dinv, (float4*)Z, st, N);
  k_stats<<<512, sblk, 0, stream>>>(Z, st, N);

  // layer 4
  k_lin4<<<gN, B, 0, stream>>>(Z, Wf + 21504, st, g3, be3, flag, dinv, hs2, N, invN);
  k_agg2<<<gN, B, 0, stream>>>((const float2*)hs2, rowst, csr, dinv, b4, flag, d_out, N);
}

// Round 6
// 547.590 us; speedup vs baseline: 2.4972x; 1.0995x over previous
//
#include <hip/hip_runtime.h>
#include <hip/hip_bf16.h>

// ---------- dtype-dispatched load helpers ----------
__device__ __forceinline__ float ldf(const void* p, size_t i, float isf){
  if (isf > 0.5f) return ((const float*)p)[i];
  unsigned int u = ((unsigned int)((const unsigned short*)p)[i]) << 16;
  return __uint_as_float(u);
}
__device__ __forceinline__ unsigned short f2bf(float v){
  unsigned int u = __float_as_uint(v);
  u = (u + 0x7FFFu + ((u >> 16) & 1u)) >> 16;   // RNE
  return (unsigned short)u;
}
__device__ __forceinline__ unsigned int pk2(float a, float b){
  return (unsigned int)f2bf(a) | ((unsigned int)f2bf(b) << 16);
}
__device__ __forceinline__ float lo16(unsigned int u){ return __uint_as_float(u << 16); }
__device__ __forceinline__ float hi16(unsigned int u){ return __uint_as_float(u & 0xFFFF0000u); }

// ---------- diagnostics ----------
__global__ void k_fill(unsigned short* o, unsigned short v, int n){
  int i = blockIdx.x*blockDim.x + threadIdx.x;
  if (i < n) o[i] = v;
}

// ---------- dtype detector: flag[0]=x_is_f32, flag[1]=idx_is_i64 ----------
__global__ void k_detect(const unsigned short* xh, const unsigned int* eu,
                         float* flag, int nelemX, long long E){
  __shared__ int sf32, si64;
  if (threadIdx.x == 0){ sf32 = 0; si64 = 1; }
  __syncthreads();
  int t = threadIdx.x;
  int i = 2*t;
  if (i < nelemX){
    unsigned e8 = (xh[i] >> 7) & 0xFFu;
    if (e8 >= 140u) sf32 = 1;
  }
  if ((long long)(2*t + 1) < 2*E){
    if (eu[2*t + 1] != 0u) si64 = 0;
  }
  __syncthreads();
  if (t == 0){ flag[0] = (float)sf32; flag[1] = (float)si64; }
}

// ---------- weight pre-convert ----------
__global__ void k_cvtW(const void* W1, const void* W2, const void* W3, const void* W4,
                       const float* __restrict__ flag, float* __restrict__ Wf){
  float isf = flag[0];
  int t = blockIdx.x*blockDim.x + threadIdx.x;
  if (t < 3072)            Wf[t] = ldf(W1, t, isf);
  else if (t < 12288)      Wf[t] = ldf(W2, t - 3072, isf);
  else if (t < 21504)      Wf[t] = ldf(W3, t - 12288, isf);
  else if (t < 21696)      Wf[t] = ldf(W4, t - 21504, isf);
}

// ---------- CSR build ----------
__global__ void k_cnt(const int* __restrict__ ei, const float* __restrict__ flag,
                      int* __restrict__ cnt, long long E, int n){
  long long i = (long long)blockIdx.x*blockDim.x + threadIdx.x;
  if (i >= E) return;
  int d = (flag[1] > 0.5f) ? ei[2*E + 2*i] : ei[E + i];
  if ((unsigned)d < (unsigned)n) atomicAdd(&cnt[d], 1);
}

__global__ void k_bsum(const int* __restrict__ cnt, int* __restrict__ bsum, int n){
  int i = blockIdx.x*256 + threadIdx.x;
  int v = (i < n) ? cnt[i] : 0;
  #pragma unroll
  for (int off = 32; off; off >>= 1) v += __shfl_down(v, off, 64);
  __shared__ int w[4];
  if ((threadIdx.x & 63) == 0) w[threadIdx.x >> 6] = v;
  __syncthreads();
  if (threadIdx.x == 0) bsum[blockIdx.x] = w[0]+w[1]+w[2]+w[3];
}

// 1 block, 256 threads: exclusive scan of bsum[nb] -> boff; rowstN = total
__global__ void k_sscan(const int* __restrict__ bsum, int* __restrict__ boff,
                        int* __restrict__ rowstN, int nb){
  int t = threadIdx.x;
  int v = (t < nb) ? bsum[t] : 0;
  int lane = t & 63, wid = t >> 6;
  int s = v;
  #pragma unroll
  for (int off = 1; off < 64; off <<= 1){
    int u = __shfl_up(s, off, 64);
    if (lane >= off) s += u;
  }
  __shared__ int wt[4];
  if (lane == 63) wt[wid] = s;
  __syncthreads();
  int add = 0;
  for (int w = 0; w < wid; ++w) add += wt[w];
  int incl = s + add;
  if (t < nb) boff[t] = incl - v;
  if (t == nb - 1) *rowstN = incl;
}

__global__ void k_emit(const int* __restrict__ cnt, const int* __restrict__ boff,
                       int* __restrict__ rowst, float* __restrict__ dinv, int n){
  int i = blockIdx.x*256 + threadIdx.x;
  int v = (i < n) ? cnt[i] : 0;
  int lane = threadIdx.x & 63, wid = threadIdx.x >> 6;
  int s = v;
  #pragma unroll
  for (int off = 1; off < 64; off <<= 1){
    int u = __shfl_up(s, off, 64);
    if (lane >= off) s += u;
  }
  __shared__ int wt[4];
  if (lane == 63) wt[wid] = s;
  __syncthreads();
  int add = 0;
  for (int w = 0; w < wid; ++w) add += wt[w];
  if (i < n){
    rowst[i] = boff[blockIdx.x] + add + s - v;
    dinv[i]  = rsqrtf((float)(1 + v));
  }
}

__global__ void k_fill_slots(const int* __restrict__ ei, const float* __restrict__ flag,
                             const int* __restrict__ rowst, int* __restrict__ cursor,
                             int* __restrict__ csr, long long E, int n){
  long long i = (long long)blockIdx.x*blockDim.x + threadIdx.x;
  if (i >= E) return;
  int s, d;
  if (flag[1] > 0.5f){ s = ei[2*i]; d = ei[2*E + 2*i]; }
  else               { s = ei[i];   d = ei[E + i];     }
  if ((unsigned)s < (unsigned)n && (unsigned)d < (unsigned)n){
    int p = atomicAdd(&cursor[d], 1);
    csr[rowst[d] + p] = s;
  }
}

// ---------- layer 1: x -> HS (bf16) ----------
// block: 4 waves over 64 nodes; wave p computes output-quarter [24p,24p+24).
// acc[24]/thread -> no spills; wave-uniform W addresses -> s_load path.
__global__ __launch_bounds__(256) void k_lin1(const void* __restrict__ x,
      const float* __restrict__ Wf, const float* __restrict__ flag,
      const float* __restrict__ dinv, unsigned short* __restrict__ HS, int n){
  int t = threadIdx.x;
  int wv = t >> 6, lane = t & 63;
  int node = blockIdx.x*64 + lane;
  if (node >= n) return;
  float isf = flag[0];
  const float* wq = Wf + 24*wv;
  float acc[24];
  #pragma unroll
  for (int f = 0; f < 24; ++f) acc[f] = 0.f;
  for (int k = 0; k < 32; ++k){
    float xk = ldf(x, (size_t)32*node + k, isf);
    const float4* wr = (const float4*)(wq + 96*k);
    #pragma unroll
    for (int f4 = 0; f4 < 6; ++f4){
      float4 w = wr[f4];
      acc[4*f4]   += xk*w.x; acc[4*f4+1] += xk*w.y;
      acc[4*f4+2] += xk*w.z; acc[4*f4+3] += xk*w.w;
    }
  }
  float di = dinv[node];
  uint4* hp = (uint4*)(HS + (size_t)96*node + 24*wv);
  #pragma unroll
  for (int q = 0; q < 3; ++q){
    uint4 o;
    o.x = pk2(di*acc[8*q],   di*acc[8*q+1]);
    o.y = pk2(di*acc[8*q+2], di*acc[8*q+3]);
    o.z = pk2(di*acc[8*q+4], di*acc[8*q+5]);
    o.w = pk2(di*acc[8*q+6], di*acc[8*q+7]);
    hp[q] = o;
  }
}

// ---------- mid layers: BN+ReLU+GEMM -> HS (bf16), wave-quarter structure ----------
__global__ __launch_bounds__(256) void k_lin(const float* __restrict__ z,
      const float* __restrict__ Wf, const float* __restrict__ st,
      const void* __restrict__ gam, const void* __restrict__ bet,
      const float* __restrict__ flag, const float* __restrict__ dinv,
      unsigned short* __restrict__ HS, int n, float invN){
  __shared__ float sa[96], sc[96];
  int t = threadIdx.x;
  if (t < 96){
    float isf = flag[0];
    float mu  = st[t]*invN;
    float var = fmaxf(st[96+t]*invN - mu*mu, 0.f);
    float istd = rsqrtf(var + 1e-5f);
    float a = ldf(gam, t, isf)*istd;
    sa[t] = a; sc[t] = ldf(bet, t, isf) - mu*a;
  }
  __syncthreads();
  int wv = t >> 6, lane = t & 63;
  int node = blockIdx.x*64 + lane;
  if (node >= n) return;
  const float* wq = Wf + 24*wv;
  float acc[24];
  #pragma unroll
  for (int f = 0; f < 24; ++f) acc[f] = 0.f;
  const float* zr = z + (size_t)96*node;
  for (int k = 0; k < 96; k += 4){
    float4 zz = *(const float4*)(zr + k);
    float y0 = fmaxf(zz.x*sa[k]   + sc[k],   0.f);
    float y1 = fmaxf(zz.y*sa[k+1] + sc[k+1], 0.f);
    float y2 = fmaxf(zz.z*sa[k+2] + sc[k+2], 0.f);
    float y3 = fmaxf(zz.w*sa[k+3] + sc[k+3], 0.f);
    const float4* wr0 = (const float4*)(wq + 96*k);
    const float4* wr1 = (const float4*)(wq + 96*(k+1));
    const float4* wr2 = (const float4*)(wq + 96*(k+2));
    const float4* wr3 = (const float4*)(wq + 96*(k+3));
    #pragma unroll
    for (int f4 = 0; f4 < 6; ++f4){
      float4 w0 = wr0[f4], w1 = wr1[f4], w2 = wr2[f4], w3 = wr3[f4];
      acc[4*f4]   += y0*w0.x + y1*w1.x + y2*w2.x + y3*w3.x;
      acc[4*f4+1] += y0*w0.y + y1*w1.y + y2*w2.y + y3*w3.y;
      acc[4*f4+2] += y0*w0.z + y1*w1.z + y2*w2.z + y3*w3.z;
      acc[4*f4+3] += y0*w0.w + y1*w1.w + y2*w2.w + y3*w3.w;
    }
  }
  float di = dinv[node];
  uint4* hp = (uint4*)(HS + (size_t)96*node + 24*wv);
  #pragma unroll
  for (int q = 0; q < 3; ++q){
    uint4 o;
    o.x = pk2(di*acc[8*q],   di*acc[8*q+1]);
    o.y = pk2(di*acc[8*q+2], di*acc[8*q+3]);
    o.z = pk2(di*acc[8*q+4], di*acc[8*q+5]);
    o.w = pk2(di*acc[8*q+6], di*acc[8*q+7]);
    hp[q] = o;
  }
}

__global__ __launch_bounds__(256) void k_lin4(const float* __restrict__ z,
      const float* __restrict__ Wf, const float* __restrict__ st,
      const void* __restrict__ gam, const void* __restrict__ bet,
      const float* __restrict__ flag, const float* __restrict__ dinv,
      float* __restrict__ hs2, int n, float invN){
  __shared__ float sa[96], sc[96];
  int t = threadIdx.x;
  if (t < 96){
    float isf = flag[0];
    float mu  = st[t]*invN;
    float var = fmaxf(st[96+t]*invN - mu*mu, 0.f);
    float istd = rsqrtf(var + 1e-5f);
    float a = ldf(gam, t, isf)*istd;
    sa[t] = a; sc[t] = ldf(bet, t, isf) - mu*a;
  }
  __syncthreads();
  int i = blockIdx.x*blockDim.x + t;
  if (i >= n) return;
  const float* zr = z + (size_t)96*i;
  float a0 = 0.f, a1 = 0.f;
  for (int k = 0; k < 96; k += 4){
    float4 zz = *(const float4*)(zr + k);
    float y0 = fmaxf(zz.x*sa[k]   + sc[k],   0.f);
    float y1 = fmaxf(zz.y*sa[k+1] + sc[k+1], 0.f);
    float y2 = fmaxf(zz.z*sa[k+2] + sc[k+2], 0.f);
    float y3 = fmaxf(zz.w*sa[k+3] + sc[k+3], 0.f);
    a0 += y0*Wf[2*k] + y1*Wf[2*k+2] + y2*Wf[2*k+4] + y3*Wf[2*k+6];
    a1 += y0*Wf[2*k+1] + y1*Wf[2*k+3] + y2*Wf[2*k+5] + y3*Wf[2*k+7];
  }
  float di = dinv[i];
  hs2[(size_t)2*i]   = di*a0;
  hs2[(size_t)2*i+1] = di*a1;
}

// ---------- CSR gather aggregation (bf16 HS): z[d] = dinv[d]*(hs[d] + sum hs[src]) ----------
#define ACC8(v) { a0+=lo16((v).x); a1+=hi16((v).x); a2+=lo16((v).y); a3+=hi16((v).y); \
                  a4+=lo16((v).z); a5+=hi16((v).z); a6+=lo16((v).w); a7+=hi16((v).w); }
__global__ __launch_bounds__(192) void k_agg(const uint4* __restrict__ hsr,
      const int* __restrict__ rowst, const int* __restrict__ csr,
      const float* __restrict__ dinv, float4* __restrict__ z4,
      float* __restrict__ st, int n){
  int t = threadIdx.y*12 + threadIdx.x;
  if (blockIdx.x == 0 && t < 192) st[t] = 0.f;   // zero stats for the following k_stats
  int node = blockIdx.x*16 + threadIdx.y;
  if (node >= n) return;
  int g = threadIdx.x;
  uint4 v = hsr[(size_t)node*12 + g];            // self-loop term
  float a0 = lo16(v.x), a1 = hi16(v.x), a2 = lo16(v.y), a3 = hi16(v.y);
  float a4 = lo16(v.z), a5 = hi16(v.z), a6 = lo16(v.w), a7 = hi16(v.w);
  int b = rowst[node], e = rowst[node+1];
  int j = b;
  for (; j + 3 < e; j += 4){
    int s0 = csr[j], s1 = csr[j+1], s2 = csr[j+2], s3 = csr[j+3];
    uint4 v0 = hsr[(size_t)s0*12 + g];
    uint4 v1 = hsr[(size_t)s1*12 + g];
    uint4 v2 = hsr[(size_t)s2*12 + g];
    uint4 v3 = hsr[(size_t)s3*12 + g];
    ACC8(v0); ACC8(v1); ACC8(v2); ACC8(v3);
  }
  for (; j < e; ++j){
    uint4 vv = hsr[(size_t)csr[j]*12 + g];
    ACC8(vv);
  }
  float di = dinv[node];
  z4[(size_t)node*24 + 2*g]     = make_float4(a0*di, a1*di, a2*di, a3*di);
  z4[(size_t)node*24 + 2*g + 1] = make_float4(a4*di, a5*di, a6*di, a7*di);
}

// final layer aggregation + bias + output convert (hs2 fp32)
__global__ void k_agg2(const float2* __restrict__ hs2, const int* __restrict__ rowst,
                       const int* __restrict__ csr, const float* __restrict__ dinv,
                       const void* __restrict__ b4, const float* __restrict__ flag,
                       void* __restrict__ out, int n){
  int node = blockIdx.x*blockDim.x + threadIdx.x;
  if (node >= n) return;
  float2 a = hs2[node];
  int b = rowst[node], e = rowst[node+1];
  for (int j = b; j < e; ++j){
    float2 v = hs2[csr[j]];
    a.x += v.x; a.y += v.y;
  }
  float isf = flag[0];
  float di = dinv[node];
  float v0 = a.x*di + ldf(b4, 0, isf);
  float v1 = a.y*di + ldf(b4, 1, isf);
  if (isf > 0.5f){
    ((float*)out)[(size_t)2*node]   = v0;
    ((float*)out)[(size_t)2*node+1] = v1;
  } else {
    ((unsigned short*)out)[(size_t)2*node]   = f2bf(v0);
    ((unsigned short*)out)[(size_t)2*node+1] = f2bf(v1);
  }
}

// ---------- batchnorm stats (sums into st[0:192], zeroed by preceding k_agg) ----------
__global__ void k_stats(const float* __restrict__ z, float* __restrict__ st, int n){
  int f = threadIdx.x, ty = threadIdx.y;
  float s = 0.f, q = 0.f;
  for (int i = blockIdx.x*4 + ty; i < n; i += gridDim.x*4){
    float y = z[(size_t)96*i + f];
    s += y; q += y*y;
  }
  __shared__ float ls[4][96], lq[4][96];
  ls[ty][f] = s; lq[ty][f] = q;
  __syncthreads();
  if (ty == 0){
    s = ls[0][f]+ls[1][f]+ls[2][f]+ls[3][f];
    q = lq[0][f]+lq[1][f]+lq[2][f]+lq[3][f];
    atomicAdd(&st[f], s); atomicAdd(&st[96+f], q);
  }
}

extern "C" void kernel_launch(void* const* d_in, const int* in_sizes, int n_in,
                              void* d_out, int out_size, void* d_ws, size_t ws_size,
                              hipStream_t stream)
{
  const int B = 256;
  unsigned short* outh = (unsigned short*)d_out;

  if (n_in < 16){
    k_fill<<<(out_size+B-1)/B, B, 0, stream>>>(outh, 0x3F40u, out_size); return;
  }
  const int N = in_sizes[0] / 32;
  const long long E = in_sizes[1] / 2;
  if (in_sizes[0] % 32 != 0 || out_size != 2*N){
    k_fill<<<(out_size+B-1)/B, B, 0, stream>>>(outh, 0x3F60u, out_size); return;
  }

  // ---- workspace layout ----
  size_t Npad = ((size_t)N + 3) & ~(size_t)3;
  float* ws   = (float*)d_ws;
  float* dinv = ws;                               // Npad
  float* Z    = dinv + Npad;                      // 96N (fp32)
  float* hs2  = Z + (size_t)96*N;                 // 2N
  float* st   = hs2 + (size_t)2*N;                // 384
  float* flag = st + 384;                         // 4
  float* Wf   = flag + 4;                         // 21696
  int* cnt    = (int*)(Wf + 21696);               // N
  int* cursor = cnt + N;                          // N (adjacent: one memset)
  int* rowst  = cursor + N;                       // N+1
  int* bsum   = rowst + N + 1;                    // 256
  int* boff   = bsum + 256;                       // 256
  int* csr    = boff + 256;                       // E
  uintptr_t hp_ = (uintptr_t)(csr + E);
  hp_ = (hp_ + 15) & ~(uintptr_t)15;
  unsigned short* HS = (unsigned short*)hp_;      // 96N bf16, 16B-aligned

  size_t needB = (hp_ - (uintptr_t)d_ws) + (size_t)96*N*2 + 64;
  if (ws_size < needB){
    k_fill<<<(out_size+B-1)/B, B, 0, stream>>>(outh, 0x3F00u, out_size); return;
  }

  const void* x  = d_in[0];
  const int*  ei = (const int*)d_in[1];
  const void* W1 = d_in[2];
  const void* g1 = d_in[4];  const void* be1 = d_in[5];
  const void* W2 = d_in[6];
  const void* g2 = d_in[8];  const void* be2 = d_in[9];
  const void* W3 = d_in[10];
  const void* g3 = d_in[12]; const void* be3 = d_in[13];
  const void* W4 = d_in[14];
  const void* b4 = d_in[15];

  int gN  = (N + B - 1)/B;
  int gE  = (int)((E + B - 1)/B);
  int nb  = (N + 255)/256;            // <= 256 assumed (N <= 65536)
  int gA  = (N + 15)/16;
  int gL  = (N + 63)/64;              // wave-quarter lin kernels: 64 nodes/block
  float invN = 1.0f / (float)N;
  dim3 ablk(12,16);
  dim3 sblk(96,4);

  // dtype detection + weight convert + CSR build
  k_detect<<<1, 256, 0, stream>>>((const unsigned short*)x, (const unsigned int*)ei,
                                  flag, in_sizes[0], E);
  hipMemsetAsync(cnt, 0, (size_t)2*N*sizeof(int), stream);   // cnt + cursor
  k_cvtW<<<(21696+B-1)/B, B, 0, stream>>>(W1, W2, W3, W4, flag, Wf);
  k_cnt<<<gE, B, 0, stream>>>(ei, flag, cnt, E, N);
  k_bsum<<<nb, 256, 0, stream>>>(cnt, bsum, N);
  k_sscan<<<1, 256, 0, stream>>>(bsum, boff, rowst + N, nb);
  k_emit<<<nb, 256, 0, stream>>>(cnt, boff, rowst, dinv, N);
  k_fill_slots<<<gE, B, 0, stream>>>(ei, flag, rowst, cursor, csr, E, N);

  // layer 1
  k_lin1<<<gL, B, 0, stream>>>(x, Wf, flag, dinv, HS, N);
  k_agg<<<gA, ablk, 0, stream>>>((const uint4*)HS, rowst, csr, dinv, (float4*)Z, st, N);
  k_stats<<<512, sblk, 0, stream>>>(Z, st, N);

  // layer 2
  k_lin<<<gL, B, 0, stream>>>(Z, Wf + 3072, st, g1, be1, flag, dinv, HS, N, invN);
  k_agg<<<gA, ablk, 0, stream>>>((const uint4*)HS, rowst, csr, dinv, (float4*)Z, st, N);
  k_stats<<<512, sblk, 0, stream>>>(Z, st, N);

  // layer 3
  k_lin<<<gL, B, 0, stream>>>(Z, Wf + 12288, st, g2, be2, flag, dinv, HS, N, invN);
  k_agg<<<gA, ablk, 0, stream>>>((const uint4*)HS, rowst, csr, dinv, (float4*)Z, st, N);
  k_stats<<<512, sblk, 0, stream>>>(Z, st, N);

  // layer 4
  k_lin4<<<gN, B, 0, stream>>>(Z, Wf + 21504, st, g3, be3, flag, dinv, hs2, N, invN);
  k_agg2<<<gN, B, 0, stream>>>((const float2*)hs2, rowst, csr, dinv, b4, flag, d_out, N);
}

// Round 7
// 381.442 us; speedup vs baseline: 3.5849x; 1.4356x over previous
//
#include <hip/hip_runtime.h>
#include <hip/hip_bf16.h>

using bf16x8 = __attribute__((ext_vector_type(8))) short;
using f32x4  = __attribute__((ext_vector_type(4))) float;

// ---------- dtype-dispatched load helpers ----------
__device__ __forceinline__ float ldf(const void* p, size_t i, float isf){
  if (isf > 0.5f) return ((const float*)p)[i];
  unsigned int u = ((unsigned int)((const unsigned short*)p)[i]) << 16;
  return __uint_as_float(u);
}
__device__ __forceinline__ unsigned short f2bf(float v){
  unsigned int u = __float_as_uint(v);
  u = (u + 0x7FFFu + ((u >> 16) & 1u)) >> 16;   // RNE
  return (unsigned short)u;
}
__device__ __forceinline__ unsigned int pk2(float a, float b){
  return (unsigned int)f2bf(a) | ((unsigned int)f2bf(b) << 16);
}
__device__ __forceinline__ float lo16(unsigned int u){ return __uint_as_float(u << 16); }
__device__ __forceinline__ float hi16(unsigned int u){ return __uint_as_float(u & 0xFFFF0000u); }

// ---------- diagnostics ----------
__global__ void k_fill(unsigned short* o, unsigned short v, int n){
  int i = blockIdx.x*blockDim.x + threadIdx.x;
  if (i < n) o[i] = v;
}

// ---------- dtype detector ----------
__global__ void k_detect(const unsigned short* xh, const unsigned int* eu,
                         float* flag, int nelemX, long long E){
  __shared__ int sf32, si64;
  if (threadIdx.x == 0){ sf32 = 0; si64 = 1; }
  __syncthreads();
  int t = threadIdx.x;
  int i = 2*t;
  if (i < nelemX){
    unsigned e8 = (xh[i] >> 7) & 0xFFu;
    if (e8 >= 140u) sf32 = 1;
  }
  if ((long long)(2*t + 1) < 2*E){
    if (eu[2*t + 1] != 0u) si64 = 0;
  }
  __syncthreads();
  if (t == 0){ flag[0] = (float)sf32; flag[1] = (float)si64; }
}

// ---------- weight pre-convert: transposed bf16 for MFMA B-operand, fp32 for W4 ----------
// Wt*[n][k] layout (row-major in n, k contiguous).
__global__ void k_cvtW(const void* W1, const void* W2, const void* W3, const void* W4,
                       const float* __restrict__ flag,
                       unsigned short* __restrict__ Wt1, unsigned short* __restrict__ Wt2,
                       unsigned short* __restrict__ Wt3, float* __restrict__ W4f){
  float isf = flag[0];
  int t = blockIdx.x*blockDim.x + threadIdx.x;
  if (t < 3072){ int nn = t >> 5, k = t & 31; Wt1[t] = f2bf(ldf(W1, (size_t)96*k + nn, isf)); }
  if (t < 9216){
    int nn = t/96, k = t - 96*nn;
    Wt2[t] = f2bf(ldf(W2, (size_t)96*k + nn, isf));
    Wt3[t] = f2bf(ldf(W3, (size_t)96*k + nn, isf));
  }
  if (t < 192) W4f[t] = ldf(W4, t, isf);
}

// ---------- CSR build ----------
__global__ void k_cnt(const int* __restrict__ ei, const float* __restrict__ flag,
                      int* __restrict__ cnt, long long E, int n){
  long long i = (long long)blockIdx.x*blockDim.x + threadIdx.x;
  if (i >= E) return;
  int d = (flag[1] > 0.5f) ? ei[2*E + 2*i] : ei[E + i];
  if ((unsigned)d < (unsigned)n) atomicAdd(&cnt[d], 1);
}

__global__ void k_bsum(const int* __restrict__ cnt, int* __restrict__ bsum, int n){
  int i = blockIdx.x*256 + threadIdx.x;
  int v = (i < n) ? cnt[i] : 0;
  #pragma unroll
  for (int off = 32; off; off >>= 1) v += __shfl_down(v, off, 64);
  __shared__ int w[4];
  if ((threadIdx.x & 63) == 0) w[threadIdx.x >> 6] = v;
  __syncthreads();
  if (threadIdx.x == 0) bsum[blockIdx.x] = w[0]+w[1]+w[2]+w[3];
}

__global__ void k_sscan(const int* __restrict__ bsum, int* __restrict__ boff,
                        int* __restrict__ rowstN, int nb){
  int t = threadIdx.x;
  int v = (t < nb) ? bsum[t] : 0;
  int lane = t & 63, wid = t >> 6;
  int s = v;
  #pragma unroll
  for (int off = 1; off < 64; off <<= 1){
    int u = __shfl_up(s, off, 64);
    if (lane >= off) s += u;
  }
  __shared__ int wt[4];
  if (lane == 63) wt[wid] = s;
  __syncthreads();
  int add = 0;
  for (int w = 0; w < wid; ++w) add += wt[w];
  int incl = s + add;
  if (t < nb) boff[t] = incl - v;
  if (t == nb - 1) *rowstN = incl;
}

__global__ void k_emit(const int* __restrict__ cnt, const int* __restrict__ boff,
                       int* __restrict__ rowst, float* __restrict__ dinv, int n){
  int i = blockIdx.x*256 + threadIdx.x;
  int v = (i < n) ? cnt[i] : 0;
  int lane = threadIdx.x & 63, wid = threadIdx.x >> 6;
  int s = v;
  #pragma unroll
  for (int off = 1; off < 64; off <<= 1){
    int u = __shfl_up(s, off, 64);
    if (lane >= off) s += u;
  }
  __shared__ int wt[4];
  if (lane == 63) wt[wid] = s;
  __syncthreads();
  int add = 0;
  for (int w = 0; w < wid; ++w) add += wt[w];
  if (i < n){
    rowst[i] = boff[blockIdx.x] + add + s - v;
    dinv[i]  = rsqrtf((float)(1 + v));
  }
}

__global__ void k_fill_slots(const int* __restrict__ ei, const float* __restrict__ flag,
                             const int* __restrict__ rowst, int* __restrict__ cursor,
                             int* __restrict__ csr, long long E, int n){
  long long i = (long long)blockIdx.x*blockDim.x + threadIdx.x;
  if (i >= E) return;
  int s, d;
  if (flag[1] > 0.5f){ s = ei[2*i]; d = ei[2*E + 2*i]; }
  else               { s = ei[i];   d = ei[E + i];     }
  if ((unsigned)s < (unsigned)n && (unsigned)d < (unsigned)n){
    int p = atomicAdd(&cursor[d], 1);
    csr[rowst[d] + p] = s;
  }
}

// ---------- MFMA layer 1: HS = dinv * (x @ W1), x N*32 ----------
// 64 nodes/block, 4 waves; wave w: rows 16w..16w+15, 6 col-tiles, K=32 (1 MFMA each).
__global__ __launch_bounds__(256) void k_lin1m(const void* __restrict__ x,
      const unsigned short* __restrict__ Wt1b, const float* __restrict__ flag,
      const float* __restrict__ dinv, unsigned short* __restrict__ HS, int n){
  __shared__ __align__(16) unsigned short Xs[64][40];   // pad 32->40: 2-way bank (free)
  __shared__ __align__(16) unsigned short Wt[96][40];
  int t = threadIdx.x;
  float isf = flag[0];
  // stage W1^T (96x32 = 384 uint4)
  for (int q = t; q < 384; q += 256){
    uint4 v = ((const uint4*)Wt1b)[q];
    *(uint4*)&Wt[q >> 2][(q & 3)*8] = v;
  }
  // stage X tile (64 rows x 32)
  {
    int row = t >> 2, part = t & 3;
    int node = blockIdx.x*64 + row;
    uint4 o;
    if (node < n){
      if (isf > 0.5f){
        const float* xr = (const float*)x + (size_t)32*node + 8*part;
        o.x = pk2(xr[0], xr[1]); o.y = pk2(xr[2], xr[3]);
        o.z = pk2(xr[4], xr[5]); o.w = pk2(xr[6], xr[7]);
      } else {
        o = ((const uint4*)x)[(size_t)4*node + part];
      }
    } else { o.x = o.y = o.z = o.w = 0u; }
    *(uint4*)&Xs[row][8*part] = o;
  }
  __syncthreads();

  int wv = t >> 6, lane = t & 63;
  int m = lane & 15, quad = lane >> 4;
  bf16x8 av = *(const bf16x8*)&Xs[16*wv + m][8*quad];
  f32x4 acc[6];
  #pragma unroll
  for (int c = 0; c < 6; ++c) acc[c] = (f32x4)(0.f);
  #pragma unroll
  for (int c = 0; c < 6; ++c){
    bf16x8 bv = *(const bf16x8*)&Wt[16*c + m][8*quad];
    acc[c] = __builtin_amdgcn_mfma_f32_16x16x32_bf16(av, bv, acc[c], 0, 0, 0);
  }
  int rowbase = blockIdx.x*64 + 16*wv + 4*quad;
  float div[4];
  #pragma unroll
  for (int r = 0; r < 4; ++r){ int rr = rowbase + r; div[r] = (rr < n) ? dinv[rr] : 0.f; }
  #pragma unroll
  for (int c = 0; c < 6; ++c){
    int col = 16*c + m;
    #pragma unroll
    for (int r = 0; r < 4; ++r){
      int rr = rowbase + r;
      if (rr < n) HS[(size_t)96*rr + col] = f2bf(acc[c][r]*div[r]);
    }
  }
}

// ---------- MFMA mid layer: HS = dinv * (relu(BN(Z)) @ W), 96x96 ----------
__global__ __launch_bounds__(256) void k_linm(const float* __restrict__ z,
      const unsigned short* __restrict__ Wtb, const float* __restrict__ st,
      const void* __restrict__ gam, const void* __restrict__ bet,
      const float* __restrict__ flag, const float* __restrict__ dinv,
      unsigned short* __restrict__ HS, int n, float invN){
  __shared__ float sa[96], sc[96];
  __shared__ __align__(16) unsigned short Ys[64][104];  // pad 96->104: 2-way bank (free)
  __shared__ __align__(16) unsigned short Wt[96][104];
  int t = threadIdx.x;
  if (t < 96){
    float isf = flag[0];
    float mu  = st[t]*invN;
    float var = fmaxf(st[96+t]*invN - mu*mu, 0.f);
    float istd = rsqrtf(var + 1e-5f);
    float a = ldf(gam, t, isf)*istd;
    sa[t] = a; sc[t] = ldf(bet, t, isf) - mu*a;
  }
  // stage W^T (96x96 = 1152 uint4)
  for (int q = t; q < 1152; q += 256){
    uint4 v = ((const uint4*)Wtb)[q];
    *(uint4*)&Wt[q/12][8*(q - 12*(q/12))] = v;
  }
  __syncthreads();
  // stage Y tile: 64 rows x 96, 4 threads/row x 24 cols
  {
    int row = t >> 2, cb = (t & 3)*24;
    int node = blockIdx.x*64 + row;
    unsigned int* yp = (unsigned int*)&Ys[row][cb];
    if (node < n){
      const float* zr = z + (size_t)96*node + cb;
      #pragma unroll
      for (int q = 0; q < 6; ++q){
        float4 zz = *(const float4*)(zr + 4*q);
        int k = cb + 4*q;
        float y0 = fmaxf(zz.x*sa[k]   + sc[k],   0.f);
        float y1 = fmaxf(zz.y*sa[k+1] + sc[k+1], 0.f);
        float y2 = fmaxf(zz.z*sa[k+2] + sc[k+2], 0.f);
        float y3 = fmaxf(zz.w*sa[k+3] + sc[k+3], 0.f);
        yp[2*q]   = pk2(y0, y1);
        yp[2*q+1] = pk2(y2, y3);
      }
    } else {
      #pragma unroll
      for (int q = 0; q < 12; ++q) yp[q] = 0u;
    }
  }
  __syncthreads();

  int wv = t >> 6, lane = t & 63;
  int m = lane & 15, quad = lane >> 4;
  bf16x8 av[3];
  #pragma unroll
  for (int kt = 0; kt < 3; ++kt)
    av[kt] = *(const bf16x8*)&Ys[16*wv + m][32*kt + 8*quad];
  f32x4 acc[6];
  #pragma unroll
  for (int c = 0; c < 6; ++c) acc[c] = (f32x4)(0.f);
  #pragma unroll
  for (int c = 0; c < 6; ++c){
    const unsigned short* wrow = &Wt[16*c + m][8*quad];
    #pragma unroll
    for (int kt = 0; kt < 3; ++kt){
      bf16x8 bv = *(const bf16x8*)(wrow + 32*kt);
      acc[c] = __builtin_amdgcn_mfma_f32_16x16x32_bf16(av[kt], bv, acc[c], 0, 0, 0);
    }
  }
  int rowbase = blockIdx.x*64 + 16*wv + 4*quad;
  float div[4];
  #pragma unroll
  for (int r = 0; r < 4; ++r){ int rr = rowbase + r; div[r] = (rr < n) ? dinv[rr] : 0.f; }
  #pragma unroll
  for (int c = 0; c < 6; ++c){
    int col = 16*c + m;
    #pragma unroll
    for (int r = 0; r < 4; ++r){
      int rr = rowbase + r;
      if (rr < n) HS[(size_t)96*rr + col] = f2bf(acc[c][r]*div[r]);
    }
  }
}

// ---------- layer 4 (96->2, VALU) ----------
__global__ __launch_bounds__(256) void k_lin4(const float* __restrict__ z,
      const float* __restrict__ Wf, const float* __restrict__ st,
      const void* __restrict__ gam, const void* __restrict__ bet,
      const float* __restrict__ flag, const float* __restrict__ dinv,
      float* __restrict__ hs2, int n, float invN){
  __shared__ float sa[96], sc[96];
  int t = threadIdx.x;
  if (t < 96){
    float isf = flag[0];
    float mu  = st[t]*invN;
    float var = fmaxf(st[96+t]*invN - mu*mu, 0.f);
    float istd = rsqrtf(var + 1e-5f);
    float a = ldf(gam, t, isf)*istd;
    sa[t] = a; sc[t] = ldf(bet, t, isf) - mu*a;
  }
  __syncthreads();
  int i = blockIdx.x*blockDim.x + t;
  if (i >= n) return;
  const float* zr = z + (size_t)96*i;
  float a0 = 0.f, a1 = 0.f;
  for (int k = 0; k < 96; k += 4){
    float4 zz = *(const float4*)(zr + k);
    float y0 = fmaxf(zz.x*sa[k]   + sc[k],   0.f);
    float y1 = fmaxf(zz.y*sa[k+1] + sc[k+1], 0.f);
    float y2 = fmaxf(zz.z*sa[k+2] + sc[k+2], 0.f);
    float y3 = fmaxf(zz.w*sa[k+3] + sc[k+3], 0.f);
    a0 += y0*Wf[2*k] + y1*Wf[2*k+2] + y2*Wf[2*k+4] + y3*Wf[2*k+6];
    a1 += y0*Wf[2*k+1] + y1*Wf[2*k+3] + y2*Wf[2*k+5] + y3*Wf[2*k+7];
  }
  float di = dinv[i];
  hs2[(size_t)2*i]   = di*a0;
  hs2[(size_t)2*i+1] = di*a1;
}

// ---------- CSR gather aggregation (bf16 HS) ----------
#define ACC8(v) { a0+=lo16((v).x); a1+=hi16((v).x); a2+=lo16((v).y); a3+=hi16((v).y); \
                  a4+=lo16((v).z); a5+=hi16((v).z); a6+=lo16((v).w); a7+=hi16((v).w); }
__global__ __launch_bounds__(192) void k_agg(const uint4* __restrict__ hsr,
      const int* __restrict__ rowst, const int* __restrict__ csr,
      const float* __restrict__ dinv, float4* __restrict__ z4,
      float* __restrict__ st, int n){
  int t = threadIdx.y*12 + threadIdx.x;
  if (blockIdx.x == 0 && t < 192) st[t] = 0.f;   // zero stats for the following k_stats
  int node = blockIdx.x*16 + threadIdx.y;
  if (node >= n) return;
  int g = threadIdx.x;
  uint4 v = hsr[(size_t)node*12 + g];            // self-loop term
  float a0 = lo16(v.x), a1 = hi16(v.x), a2 = lo16(v.y), a3 = hi16(v.y);
  float a4 = lo16(v.z), a5 = hi16(v.z), a6 = lo16(v.w), a7 = hi16(v.w);
  int b = rowst[node], e = rowst[node+1];
  int j = b;
  for (; j + 3 < e; j += 4){
    int s0 = csr[j], s1 = csr[j+1], s2 = csr[j+2], s3 = csr[j+3];
    uint4 v0 = hsr[(size_t)s0*12 + g];
    uint4 v1 = hsr[(size_t)s1*12 + g];
    uint4 v2 = hsr[(size_t)s2*12 + g];
    uint4 v3 = hsr[(size_t)s3*12 + g];
    ACC8(v0); ACC8(v1); ACC8(v2); ACC8(v3);
  }
  for (; j < e; ++j){
    uint4 vv = hsr[(size_t)csr[j]*12 + g];
    ACC8(vv);
  }
  float di = dinv[node];
  z4[(size_t)node*24 + 2*g]     = make_float4(a0*di, a1*di, a2*di, a3*di);
  z4[(size_t)node*24 + 2*g + 1] = make_float4(a4*di, a5*di, a6*di, a7*di);
}

__global__ void k_agg2(const float2* __restrict__ hs2, const int* __restrict__ rowst,
                       const int* __restrict__ csr, const float* __restrict__ dinv,
                       const void* __restrict__ b4, const float* __restrict__ flag,
                       void* __restrict__ out, int n){
  int node = blockIdx.x*blockDim.x + threadIdx.x;
  if (node >= n) return;
  float2 a = hs2[node];
  int b = rowst[node], e = rowst[node+1];
  for (int j = b; j < e; ++j){
    float2 v = hs2[csr[j]];
    a.x += v.x; a.y += v.y;
  }
  float isf = flag[0];
  float di = dinv[node];
  float v0 = a.x*di + ldf(b4, 0, isf);
  float v1 = a.y*di + ldf(b4, 1, isf);
  if (isf > 0.5f){
    ((float*)out)[(size_t)2*node]   = v0;
    ((float*)out)[(size_t)2*node+1] = v1;
  } else {
    ((unsigned short*)out)[(size_t)2*node]   = f2bf(v0);
    ((unsigned short*)out)[(size_t)2*node+1] = f2bf(v1);
  }
}

// ---------- batchnorm stats ----------
__global__ void k_stats(const float* __restrict__ z, float* __restrict__ st, int n){
  int f = threadIdx.x, ty = threadIdx.y;
  float s = 0.f, q = 0.f;
  for (int i = blockIdx.x*4 + ty; i < n; i += gridDim.x*4){
    float y = z[(size_t)96*i + f];
    s += y; q += y*y;
  }
  __shared__ float ls[4][96], lq[4][96];
  ls[ty][f] = s; lq[ty][f] = q;
  __syncthreads();
  if (ty == 0){
    s = ls[0][f]+ls[1][f]+ls[2][f]+ls[3][f];
    q = lq[0][f]+lq[1][f]+lq[2][f]+lq[3][f];
    atomicAdd(&st[f], s); atomicAdd(&st[96+f], q);
  }
}

extern "C" void kernel_launch(void* const* d_in, const int* in_sizes, int n_in,
                              void* d_out, int out_size, void* d_ws, size_t ws_size,
                              hipStream_t stream)
{
  const int B = 256;
  unsigned short* outh = (unsigned short*)d_out;

  if (n_in < 16){
    k_fill<<<(out_size+B-1)/B, B, 0, stream>>>(outh, 0x3F40u, out_size); return;
  }
  const int N = in_sizes[0] / 32;
  const long long E = in_sizes[1] / 2;
  if (in_sizes[0] % 32 != 0 || out_size != 2*N){
    k_fill<<<(out_size+B-1)/B, B, 0, stream>>>(outh, 0x3F60u, out_size); return;
  }

  // ---- workspace layout ----
  size_t Npad = ((size_t)N + 3) & ~(size_t)3;
  float* ws   = (float*)d_ws;
  float* dinv = ws;                               // Npad
  float* Z    = dinv + Npad;                      // 96N (fp32)
  float* hs2  = Z + (size_t)96*N;                 // 2N
  float* st   = hs2 + (size_t)2*N;                // 384
  float* flag = st + 384;                         // 4
  float* W4f  = flag + 4;                         // 192
  unsigned short* Wt1b = (unsigned short*)(W4f + 192);   // 3072 bf16 (16B-aligned: offset even)
  unsigned short* Wt2b = Wt1b + 3072;             // 9216
  unsigned short* Wt3b = Wt2b + 9216;             // 9216
  int* cnt    = (int*)(Wt3b + 9216);              // N
  int* cursor = cnt + N;                          // N (adjacent: one memset)
  int* rowst  = cursor + N;                       // N+1
  int* bsum   = rowst + N + 1;                    // 256
  int* boff   = bsum + 256;                       // 256
  int* csr    = boff + 256;                       // E
  uintptr_t hp_ = (uintptr_t)(csr + E);
  hp_ = (hp_ + 15) & ~(uintptr_t)15;
  unsigned short* HS = (unsigned short*)hp_;      // 96N bf16, 16B-aligned

  size_t needB = (hp_ - (uintptr_t)d_ws) + (size_t)96*N*2 + 64;
  if (ws_size < needB){
    k_fill<<<(out_size+B-1)/B, B, 0, stream>>>(outh, 0x3F00u, out_size); return;
  }

  const void* x  = d_in[0];
  const int*  ei = (const int*)d_in[1];
  const void* W1 = d_in[2];
  const void* g1 = d_in[4];  const void* be1 = d_in[5];
  const void* W2 = d_in[6];
  const void* g2 = d_in[8];  const void* be2 = d_in[9];
  const void* W3 = d_in[10];
  const void* g3 = d_in[12]; const void* be3 = d_in[13];
  const void* W4 = d_in[14];
  const void* b4 = d_in[15];

  int gN  = (N + B - 1)/B;
  int gE  = (int)((E + B - 1)/B);
  int nb  = (N + 255)/256;            // <= 256 assumed
  int gA  = (N + 15)/16;
  int gL  = (N + 63)/64;              // MFMA lin kernels: 64 nodes/block
  float invN = 1.0f / (float)N;
  dim3 ablk(12,16);
  dim3 sblk(96,4);

  // dtype detection + weight convert + CSR build
  k_detect<<<1, 256, 0, stream>>>((const unsigned short*)x, (const unsigned int*)ei,
                                  flag, in_sizes[0], E);
  hipMemsetAsync(cnt, 0, (size_t)2*N*sizeof(int), stream);   // cnt + cursor
  k_cvtW<<<(9216+B-1)/B, B, 0, stream>>>(W1, W2, W3, W4, flag, Wt1b, Wt2b, Wt3b, W4f);
  k_cnt<<<gE, B, 0, stream>>>(ei, flag, cnt, E, N);
  k_bsum<<<nb, 256, 0, stream>>>(cnt, bsum, N);
  k_sscan<<<1, 256, 0, stream>>>(bsum, boff, rowst + N, nb);
  k_emit<<<nb, 256, 0, stream>>>(cnt, boff, rowst, dinv, N);
  k_fill_slots<<<gE, B, 0, stream>>>(ei, flag, rowst, cursor, csr, E, N);

  // layer 1 (MFMA)
  k_lin1m<<<gL, B, 0, stream>>>(x, Wt1b, flag, dinv, HS, N);
  k_agg<<<gA, ablk, 0, stream>>>((const uint4*)HS, rowst, csr, dinv, (float4*)Z, st, N);
  k_stats<<<512, sblk, 0, stream>>>(Z, st, N);

  // layer 2 (MFMA)
  k_linm<<<gL, B, 0, stream>>>(Z, Wt2b, st, g1, be1, flag, dinv, HS, N, invN);
  k_agg<<<gA, ablk, 0, stream>>>((const uint4*)HS, rowst, csr, dinv, (float4*)Z, st, N);
  k_stats<<<512, sblk, 0, stream>>>(Z, st, N);

  // layer 3 (MFMA)
  k_linm<<<gL, B, 0, stream>>>(Z, Wt3b, st, g2, be2, flag, dinv, HS, N, invN);
  k_agg<<<gA, ablk, 0, stream>>>((const uint4*)HS, rowst, csr, dinv, (float4*)Z, st, N);
  k_stats<<<512, sblk, 0, stream>>>(Z, st, N);

  // layer 4
  k_lin4<<<gN, B, 0, stream>>>(Z, W4f, st, g3, be3, flag, dinv, hs2, N, invN);
  k_agg2<<<gN, B, 0, stream>>>((const float2*)hs2, rowst, csr, dinv, b4, flag, d_out, N);
}